// Round 7
// baseline (578.736 us; speedup 1.0000x reference)
//
#include <hip/hip_runtime.h>
#include <cstdint>
#include <cstddef>

#define BB 4
#define CC 2048
#define HH 48
#define WW 48
#define NN 2304       // HH*WW
#define CAMS 384

typedef unsigned short ushort_t;
typedef float f32x4 __attribute__((ext_vector_type(4)));
typedef int i32x4 __attribute__((ext_vector_type(4)));
typedef int i32x8 __attribute__((ext_vector_type(8)));

#define SCALE1 0x7F7F7F7F   // e8m0 127 = 2^0 in every byte -> scale 1.0

// ---- bf16 helpers ----
__device__ __forceinline__ ushort_t f2bf(float f) {
    uint32_t u = __builtin_bit_cast(uint32_t, f);
    u += 0x7FFFu + ((u >> 16) & 1u);
    return (ushort_t)(u >> 16);
}
__device__ __forceinline__ float bf2f(ushort_t u) {
    return __builtin_bit_cast(float, (uint32_t)u << 16);
}

// ---- fp8 e4m3 (OCP on gfx950) via HW cvt ----
__device__ __forceinline__ uint32_t pk2fp8(float a, float b) {
    return (uint32_t)__builtin_amdgcn_cvt_pk_fp8_f32(a, b, 0, false) & 0xFFFFu;
}
__device__ __forceinline__ uint8_t f2fp8(float v) {
    return (uint8_t)(pk2fp8(v, v) & 0xFFu);
}

__device__ __forceinline__ void gld16(const void* g, void* l) {
    __builtin_amdgcn_global_load_lds(
        (const __attribute__((address_space(1))) uint32_t*)g,
        (__attribute__((address_space(3))) uint32_t*)l, 16, 0, 0);
}

// ---- MX-scaled fp8 MFMA mainloop (16x16x128 f8f6f4, scales = 1.0):
// D[m0..+128][n0..+128] += A[m][k]*B[n][k]
// A: [M][K] fp8 k-fast staged via global_load_lds (16KB LDS, chunk-XOR
// layout: logical 16B chunk c of row r at physical c^(r&7); fragment =
// two b128 reads at chunks (2q)^(m&7),(2q+1)^(m&7) -- each bank touched
// exactly 8x/wave-read = structural floor).
// B: [N][K] fp8 k-fast read DIRECTLY from global into VGPRs: lane
// (col,quad) reads row n0+wn+j*16+col bytes k0+quad*32..+31 -- a wave =
// 16 rows x 128B fully-coalesced dwordx4 pairs, L2-served (tiles shared
// by 16..72 blocks). Issued BEFORE the staging barrier so L2 latency
// hides behind A-staging; no LDS hazard -> barriers protect A only.
// Per-k0 LDS traffic 96KB -> 48KB: the matrix pipe becomes the limiter.
// B's k-permutation (quad*32 lo/hi 16B) == A's logical-chunk mapping, so
// the k-reduction is exact. ----
__device__ __forceinline__ void mfma_mainloop_mx(
    const uint8_t* __restrict__ A, const uint8_t* __restrict__ B, int K,
    int m0, int n0, uint8_t* sA, f32x4 acc[4][4])
{
    const int t = threadIdx.x;
    const int lane = t & 63;
    const int w = t >> 6;
    const int wm = (w >> 1) * 64;
    const int wn = (w & 1) * 64;
    const int col = lane & 15;
    const int quad = lane >> 4;
    const int lr = lane >> 3;       // row within 8-row staging group
    const int lp = lane & 7;        // physical 16B chunk within 128B row

    const uint8_t* bp[4];
    #pragma unroll
    for (int j = 0; j < 4; j++)
        bp[j] = B + (size_t)(n0 + wn + j * 16 + col) * K + quad * 32;

    for (int k0 = 0; k0 < K; k0 += 128) {
        // B fragments: direct global -> VGPR, issued ahead of the barrier
        i32x4 blo[4], bhi[4];
        #pragma unroll
        for (int j = 0; j < 4; j++) {
            blo[j] = *(const i32x4*)(bp[j] + k0);
            bhi[j] = *(const i32x4*)(bp[j] + k0 + 16);
        }
        __syncthreads();            // prior iteration's A reads complete
        #pragma unroll
        for (int it = 0; it < 4; it++) {
            const int rg = w * 32 + it * 8;           // wave-uniform row base
            const int r = rg + lr;                    // tile-local row
            const int c = lp ^ (r & 7);               // logical chunk to fetch
            gld16(A + (size_t)(m0 + r) * K + k0 + c * 16, sA + rg * 128);
        }
        __syncthreads();            // A staged (drains vmcnt incl. B loads)
        #pragma unroll
        for (int i = 0; i < 4; i++) {
            const int m = wm + i * 16 + col;
            i32x4 lo = *(const i32x4*)(sA + m * 128 + ((2 * quad) ^ (m & 7)) * 16);
            i32x4 hi = *(const i32x4*)(sA + m * 128 + ((2 * quad + 1) ^ (m & 7)) * 16);
            i32x8 af = (i32x8){lo.x, lo.y, lo.z, lo.w, hi.x, hi.y, hi.z, hi.w};
            #pragma unroll
            for (int j = 0; j < 4; j++) {
                i32x8 bf8 = (i32x8){blo[j].x, blo[j].y, blo[j].z, blo[j].w,
                                    bhi[j].x, bhi[j].y, bhi[j].z, bhi[j].w};
                acc[i][j] = __builtin_amdgcn_mfma_scale_f32_16x16x128_f8f6f4(
                    af, bf8, acc[i][j], 0, 0,         // cbsz=fp8, blgp=fp8
                    0, SCALE1, 0, SCALE1);            // scales = 1.0
            }
        }
    }
}

// ---------------- init: zero norm + loss accumulators ----------------
__global__ void init_kernel(float* __restrict__ qn2, float* __restrict__ kn2,
                            float* __restrict__ accf) {
    int t = blockIdx.x * 256 + threadIdx.x;
    if (t < BB * NN) { qn2[t] = 0.f; kn2[t] = 0.f; }
    if (t == 0) { ((double*)accf)[0] = 0.0; ((unsigned int*)accf)[2] = 0u; }
}

// ---------------- W fp32 -> fp8 (layout unchanged, c fast) ----------------
__global__ void conv_w(const float* __restrict__ Wq, const float* __restrict__ Wk,
                       uint8_t* __restrict__ Wq8, uint8_t* __restrict__ Wk8) {
    const int per = CC * CC / 4;
    int idx = blockIdx.x * 256 + threadIdx.x;
    if (idx >= 2 * per) return;
    const float4* src; uint8_t* dst; int i;
    if (idx < per) { src = (const float4*)Wq; dst = Wq8; i = idx; }
    else           { src = (const float4*)Wk; dst = Wk8; i = idx - per; }
    float4 v = src[i];
    *(uint32_t*)(dst + (size_t)i * 4) = pk2fp8(v.x, v.y) | (pk2fp8(v.z, v.w) << 16);
}

// ---------------- x fp32 [b][c][n] -> x8 fp8 same + xT8 fp8 [b][n][c] -----
__global__ void conv_x(const float* __restrict__ x, uint8_t* __restrict__ x8,
                       uint8_t* __restrict__ xT8) {
    __shared__ float tile[32][33];
    const int b = blockIdx.z;
    const int c0 = blockIdx.y * 32, n0 = blockIdx.x * 32;
    const int t = threadIdx.x;
    {
        const int c = t >> 3, n4 = (t & 7) * 4;
        const float4 v = *(const float4*)(x + ((size_t)b * CC + c0 + c) * NN + n0 + n4);
        *(uint32_t*)(x8 + ((size_t)b * CC + c0 + c) * NN + n0 + n4) =
            pk2fp8(v.x, v.y) | (pk2fp8(v.z, v.w) << 16);
        tile[c][n4] = v.x; tile[c][n4 + 1] = v.y;
        tile[c][n4 + 2] = v.z; tile[c][n4 + 3] = v.w;
    }
    __syncthreads();
    {
        const int n = t >> 3, c4 = (t & 7) * 4;
        uint32_t u = pk2fp8(tile[c4][n], tile[c4 + 1][n])
                   | (pk2fp8(tile[c4 + 2][n], tile[c4 + 3][n]) << 16);
        *(uint32_t*)(xT8 + ((size_t)b * NN + n0 + n) * CC + c0 + c4) = u;
    }
}

// ---------------- merged proj (q and k): outT[b][n][o] = sum_c xT[n][c]*W[o][c]+bias
// grid.z = b*2 + which; fused row-norm accumulation from fp32 accs. ----
__global__ __launch_bounds__(256) void gemm_proj(
    const uint8_t* __restrict__ xT8,
    const uint8_t* __restrict__ Wq8, const uint8_t* __restrict__ Wk8,
    const float* __restrict__ bq, const float* __restrict__ bk,
    uint8_t* __restrict__ qT8, uint8_t* __restrict__ kT8,
    float* __restrict__ qn2, float* __restrict__ kn2)
{
    __shared__ __align__(16) uint8_t sA[128 * 128];
    const int z = blockIdx.z;
    const int b = z >> 1, which = z & 1;
    const uint8_t* Wb   = which ? Wk8 : Wq8;
    const float*   bias = which ? bk  : bq;
    uint8_t*       outT = which ? kT8 : qT8;
    float*         nrm  = which ? kn2 : qn2;
    const int m0 = blockIdx.y * 128;   // n
    const int n0 = blockIdx.x * 128;   // o
    f32x4 acc[4][4];
    const f32x4 zz = {0.f, 0.f, 0.f, 0.f};
    #pragma unroll
    for (int i = 0; i < 4; i++)
        #pragma unroll
        for (int j = 0; j < 4; j++) acc[i][j] = zz;
    mfma_mainloop_mx(xT8 + (size_t)b * NN * CC, Wb, CC, m0, n0, sA, acc);
    const int t = threadIdx.x, lane = t & 63, w = t >> 6;
    const int wm = (w >> 1) * 64, wn = (w & 1) * 64;
    const int col = lane & 15, quad = lane >> 4;
    uint8_t* O = outT + (size_t)b * NN * CC;
    float sq[4][4];
    #pragma unroll
    for (int i = 0; i < 4; i++)
        #pragma unroll
        for (int r = 0; r < 4; r++) sq[i][r] = 0.f;
    #pragma unroll
    for (int j = 0; j < 4; j++) {
        const int gn = n0 + wn + j * 16 + col;     // o
        const float bv = bias[gn];
        #pragma unroll
        for (int i = 0; i < 4; i++) {
            const int gm = m0 + wm + i * 16 + quad * 4;   // n
            #pragma unroll
            for (int r = 0; r < 4; r++) {
                float v = acc[i][j][r] + bv;
                O[(size_t)(gm + r) * CC + gn] = f2fp8(v);
                sq[i][r] += v * v;
            }
        }
    }
    #pragma unroll
    for (int i = 0; i < 4; i++)
        #pragma unroll
        for (int r = 0; r < 4; r++) {
            float s = sq[i][r];
            #pragma unroll
            for (int o = 1; o < 16; o <<= 1) s += __shfl_xor(s, o, 64);
            if (col == 0) {
                const int gm = m0 + wm + i * 16 + quad * 4 + r;
                atomicAdd(&nrm[b * NN + gm], s);
            }
        }
}

// ---------------- energy: S[b][n][m] = sum_o qT[n][o]*kT[m][o] (bf16 out) --
__global__ __launch_bounds__(256) void gemm_energy(
    const uint8_t* __restrict__ qT8, const uint8_t* __restrict__ kT8,
    ushort_t* __restrict__ S)
{
    __shared__ __align__(16) uint8_t sA[128 * 128];
    const int b = blockIdx.z;
    const int m0 = blockIdx.y * 128;   // n
    const int n0 = blockIdx.x * 128;   // m
    f32x4 acc[4][4];
    const f32x4 zz = {0.f, 0.f, 0.f, 0.f};
    #pragma unroll
    for (int i = 0; i < 4; i++)
        #pragma unroll
        for (int j = 0; j < 4; j++) acc[i][j] = zz;
    mfma_mainloop_mx(qT8 + (size_t)b * NN * CC, kT8 + (size_t)b * NN * CC, CC,
                     m0, n0, sA, acc);
    const int t = threadIdx.x, lane = t & 63, w = t >> 6;
    const int wm = (w >> 1) * 64, wn = (w & 1) * 64;
    const int col = lane & 15, quad = lane >> 4;
    ushort_t* O = S + (size_t)b * NN * NN;
    #pragma unroll
    for (int i = 0; i < 4; i++) {
        const int gm = m0 + wm + i * 16 + quad * 4;
        #pragma unroll
        for (int j = 0; j < 4; j++) {
            const int gn = n0 + wn + j * 16 + col;
            #pragma unroll
            for (int r = 0; r < 4; r++)
                O[(size_t)(gm + r) * NN + gn] = f2bf(acc[i][j][r]);
        }
    }
}

// ---------------- softmax row n over m, scale rsqrt(qn2*kn2), inline mask,
// write att = mask*softmax*256 as fp8 (x256 escapes e4m3 subnormal floor) --
__global__ __launch_bounds__(256) void softmax_kernel(
    const ushort_t* __restrict__ S, uint8_t* __restrict__ att,
    const float* __restrict__ qn2, const float* __restrict__ kn2,
    const float* __restrict__ cam)
{
    const int n = blockIdx.x, b = blockIdx.y;
    const ushort_t* row = S + ((size_t)b * NN + n) * NN;
    uint8_t* orow = att + ((size_t)b * NN + n) * NN;
    const float qinv = rsqrtf(qn2[b * NN + n]);
    // inline bilinear mask for this query row
    const int y = n / WW, xx = n % WW;
    const float ys = (float)(y  * (CAMS - 1)) / (float)(HH - 1);
    const float xs = (float)(xx * (CAMS - 1)) / (float)(WW - 1);
    const int y0 = (int)ys, x0 = (int)xs;
    const int y1 = min(y0 + 1, CAMS - 1), x1 = min(x0 + 1, CAMS - 1);
    const float wy = ys - (float)y0, wx = xs - (float)x0;
    const float* cb = cam + (size_t)b * CAMS * CAMS;
    float c00 = cb[y0 * CAMS + x0]; if (c00 == 255.f) c00 = 0.f;
    float c01 = cb[y0 * CAMS + x1]; if (c01 == 255.f) c01 = 0.f;
    float c10 = cb[y1 * CAMS + x0]; if (c10 == 255.f) c10 = 0.f;
    float c11 = cb[y1 * CAMS + x1]; if (c11 == 255.f) c11 = 0.f;
    const float mv = (1.f - wy) * ((1.f - wx) * c00 + wx * c01)
                   +        wy  * ((1.f - wx) * c10 + wx * c11);
    const float mval = (mv > 0.f) ? 1.f : 0.f;

    const int t = threadIdx.x;
    float v[9];
    float vmax = -3.4e38f;
    #pragma unroll
    for (int i = 0; i < 9; i++) {
        int idx = t + i * 256;
        float s = bf2f(row[idx]) * qinv * rsqrtf(kn2[b * NN + idx]);
        v[i] = s;
        vmax = fmaxf(vmax, s);
    }
    __shared__ float red[8];
    int lane = t & 63, wid = t >> 6;
    #pragma unroll
    for (int o = 32; o; o >>= 1) vmax = fmaxf(vmax, __shfl_down(vmax, o, 64));
    if (!lane) red[wid] = vmax;
    __syncthreads();
    vmax = fmaxf(fmaxf(red[0], red[1]), fmaxf(red[2], red[3]));
    float s = 0.f;
    #pragma unroll
    for (int i = 0; i < 9; i++) { v[i] = __expf(v[i] - vmax); s += v[i]; }
    #pragma unroll
    for (int o = 32; o; o >>= 1) s += __shfl_down(s, o, 64);
    if (!lane) red[4 + wid] = s;
    __syncthreads();
    s = red[4] + red[5] + red[6] + red[7];
    const float scale = mval * 256.f / s;
    #pragma unroll
    for (int i = 0; i < 9; i++) orow[t + i * 256] = f2fp8(v[i] * scale);
}

// ---------------- out: new_x[c][n] = sum_m x8[c][m]*att[n][m]; fused loss --
__global__ __launch_bounds__(256) void gemm_out_loss(
    const uint8_t* __restrict__ x8, const uint8_t* __restrict__ att,
    const float* __restrict__ x, const float* __restrict__ gamma,
    float* __restrict__ accf)
{
    __shared__ __align__(16) uint8_t sA[128 * 128];
    const int b = blockIdx.z;
    const int m0 = blockIdx.y * 128;   // c
    const int n0 = blockIdx.x * 128;   // n
    f32x4 acc[4][4];
    const f32x4 zz = {0.f, 0.f, 0.f, 0.f};
    #pragma unroll
    for (int i = 0; i < 4; i++)
        #pragma unroll
        for (int j = 0; j < 4; j++) acc[i][j] = zz;
    mfma_mainloop_mx(x8 + (size_t)b * CC * NN, att + (size_t)b * NN * NN, NN,
                     m0, n0, sA, acc);
    const int t = threadIdx.x, lane = t & 63, w = t >> 6;
    const int wm = (w >> 1) * 64, wn = (w & 1) * 64;
    const int col = lane & 15, quad = lane >> 4;
    const float g = gamma[0] * (1.f / 256.f);   // undo att x256 pre-scale
    const float* Xb = x + (size_t)b * CC * NN;
    float lsum = 0.f;
    unsigned int lcnt = 0;
    #pragma unroll
    for (int i = 0; i < 4; i++) {
        const int gm = m0 + wm + i * 16 + quad * 4;   // c
        #pragma unroll
        for (int j = 0; j < 4; j++) {
            const int gn = n0 + wn + j * 16 + col;    // n
            #pragma unroll
            for (int r = 0; r < 4; r++) {
                float xv = Xb[(size_t)(gm + r) * NN + gn];
                float d = xv - g * acc[i][j][r];
                float r2 = d * d;
                lsum += r2;
                lcnt += (r2 != 0.f) ? 1u : 0u;
            }
        }
    }
    #pragma unroll
    for (int o = 32; o; o >>= 1) {
        lsum += __shfl_down(lsum, o, 64);
        lcnt += __shfl_down(lcnt, o, 64);
    }
    __shared__ float rs[4];
    __shared__ unsigned int rc[4];
    if (!lane) { rs[w] = lsum; rc[w] = lcnt; }
    __syncthreads();
    if (t == 0) {
        double tot = (double)rs[0] + rs[1] + rs[2] + rs[3];
        unsigned int ct = rc[0] + rc[1] + rc[2] + rc[3];
        atomicAdd((double*)accf, tot);
        atomicAdd(((unsigned int*)accf) + 2, ct);
    }
}

__global__ void finalize_kernel(const float* __restrict__ accf, float* __restrict__ out) {
    double s = ((const double*)accf)[0];
    unsigned int c = ((const unsigned int*)accf)[2];
    out[0] = (float)(s / (double)c);
}

extern "C" void kernel_launch(void* const* d_in, const int* in_sizes, int n_in,
                              void* d_out, int out_size, void* d_ws, size_t ws_size,
                              hipStream_t stream) {
    const float* x     = (const float*)d_in[0];
    const float* cam   = (const float*)d_in[1];
    const float* Wq    = (const float*)d_in[2];
    const float* bq    = (const float*)d_in[3];
    const float* Wk    = (const float*)d_in[4];
    const float* bk    = (const float*)d_in[5];
    const float* gamma = (const float*)d_in[6];

    uint8_t* ws = (uint8_t*)d_ws;
    size_t off = 0;
    auto alloc = [&](size_t bytes) {
        void* p = ws + off;
        off = (off + bytes + 255) & ~(size_t)255;
        return p;
    };
    uint8_t*  qT8  = (uint8_t*)alloc((size_t)BB * NN * CC);
    uint8_t*  kT8  = (uint8_t*)alloc((size_t)BB * NN * CC);
    uint8_t*  xT8  = (uint8_t*)alloc((size_t)BB * NN * CC);
    uint8_t*  x8   = (uint8_t*)alloc((size_t)BB * CC * NN);
    uint8_t*  att  = (uint8_t*)alloc((size_t)BB * NN * NN);
    ushort_t* S    = (ushort_t*)alloc((size_t)BB * NN * NN * 2);
    uint8_t*  Wq8  = (uint8_t*)alloc((size_t)CC * CC);
    uint8_t*  Wk8  = (uint8_t*)alloc((size_t)CC * CC);
    float*    qn2  = (float*)alloc((size_t)BB * NN * 4);
    float*    kn2  = (float*)alloc((size_t)BB * NN * 4);
    float*    acc  = (float*)alloc(16);

    hipLaunchKernelGGL(init_kernel, dim3((BB * NN + 255) / 256), dim3(256), 0, stream,
                       qn2, kn2, acc);
    hipLaunchKernelGGL(conv_w, dim3(2 * CC * CC / 4 / 256), dim3(256), 0, stream,
                       Wq, Wk, Wq8, Wk8);
    hipLaunchKernelGGL(conv_x, dim3(NN / 32, CC / 32, BB), dim3(256), 0, stream,
                       x, x8, xT8);
    hipLaunchKernelGGL(gemm_proj, dim3(CC / 128, NN / 128, BB * 2), dim3(256), 0, stream,
                       xT8, Wq8, Wk8, bq, bk, qT8, kT8, qn2, kn2);
    hipLaunchKernelGGL(gemm_energy, dim3(NN / 128, NN / 128, BB), dim3(256), 0, stream,
                       qT8, kT8, S);
    hipLaunchKernelGGL(softmax_kernel, dim3(NN, BB), dim3(256), 0, stream,
                       S, att, qn2, kn2, cam);
    hipLaunchKernelGGL(gemm_out_loss, dim3(NN / 128, CC / 128, BB), dim3(256), 0, stream,
                       x8, att, x, gamma, acc);
    hipLaunchKernelGGL(finalize_kernel, dim3(1), dim3(1), 0, stream, acc, (float*)d_out);
}

// Round 8
// 434.155 us; speedup vs baseline: 1.3330x; 1.3330x over previous
//
#include <hip/hip_runtime.h>
#include <cstdint>
#include <cstddef>

#define BB 4
#define CC 2048
#define HH 48
#define WW 48
#define NN 2304       // HH*WW
#define CAMS 384

typedef unsigned short ushort_t;
typedef float f32x4 __attribute__((ext_vector_type(4)));
typedef int i32x4 __attribute__((ext_vector_type(4)));
typedef int i32x8 __attribute__((ext_vector_type(8)));

#define SCALE1 0x7F7F7F7F   // e8m0 127 = 2^0 in every byte -> scale 1.0

// ---- bf16 helpers ----
__device__ __forceinline__ ushort_t f2bf(float f) {
    uint32_t u = __builtin_bit_cast(uint32_t, f);
    u += 0x7FFFu + ((u >> 16) & 1u);
    return (ushort_t)(u >> 16);
}
__device__ __forceinline__ float bf2f(ushort_t u) {
    return __builtin_bit_cast(float, (uint32_t)u << 16);
}

// ---- fp8 e4m3 (OCP on gfx950) via HW cvt ----
__device__ __forceinline__ uint32_t pk2fp8(float a, float b) {
    return (uint32_t)__builtin_amdgcn_cvt_pk_fp8_f32(a, b, 0, false) & 0xFFFFu;
}
__device__ __forceinline__ uint8_t f2fp8(float v) {
    return (uint8_t)(pk2fp8(v, v) & 0xFFu);
}

__device__ __forceinline__ void gld16(const void* g, void* l) {
    __builtin_amdgcn_global_load_lds(
        (const __attribute__((address_space(1))) uint32_t*)g,
        (__attribute__((address_space(3))) uint32_t*)l, 16, 0, 0);
}

// ---- MX-scaled fp8 MFMA mainloop (16x16x128 f8f6f4, scales = 1.0):
// D[m0..+128][n0..+128] += A[m][k]*B[n][k]   (round-6 structure, VALU-lean)
// A,B: [M/N][K] fp8 k-fast, both staged via global_load_lds. BK=128 ->
// 16KB/buffer, 32KB total. Logical 16B chunk c of row r at physical
// c^(r&7); fragment = two ds_read_b128 at chunks (2q)^(m&7),(2q+1)^(m&7)
// -- every bank touched exactly 8x/wave-read = structural floor.
// VALU diet vs round 6: fragment LDS offsets hoisted out of the K-loop
// (k0-invariant ints), staging pointers strength-reduced, and ds_read
// results written straight into the i32x8 halves (pointer-punned) so the
// allocator forms the MFMA operand without vector-build movs. ----
__device__ __forceinline__ void mfma_mainloop_mx(
    const uint8_t* __restrict__ A, const uint8_t* __restrict__ B, int K,
    int m0, int n0, uint8_t* sA, uint8_t* sB, f32x4 acc[4][4])
{
    const int t = threadIdx.x;
    const int lane = t & 63;
    const int w = t >> 6;
    const int wm = (w >> 1) * 64;
    const int wn = (w & 1) * 64;
    const int col = lane & 15;
    const int quad = lane >> 4;
    const int lr = lane >> 3;       // row within 8-row staging group
    const int lp = lane & 7;        // physical 16B chunk within 128B row

    // staging sources (advance by +128 per k0) and wave-uniform LDS dests
    const uint8_t* ap[4];
    const uint8_t* bp[4];
    int sdst[4];
    #pragma unroll
    for (int it = 0; it < 4; it++) {
        const int rg = w * 32 + it * 8;
        const int r  = rg + lr;
        const int c  = lp ^ (r & 7);
        ap[it] = A + (size_t)(m0 + r) * K + c * 16;
        bp[it] = B + (size_t)(n0 + r) * K + c * 16;
        sdst[it] = rg * 128;
    }
    // k0-invariant LDS fragment byte-offsets
    int foA[4][2], foB[4][2];
    #pragma unroll
    for (int i = 0; i < 4; i++) {
        const int m = wm + i * 16 + col;
        foA[i][0] = m * 128 + ((2 * quad)     ^ (m & 7)) * 16;
        foA[i][1] = m * 128 + ((2 * quad + 1) ^ (m & 7)) * 16;
        const int n = wn + i * 16 + col;
        foB[i][0] = n * 128 + ((2 * quad)     ^ (n & 7)) * 16;
        foB[i][1] = n * 128 + ((2 * quad + 1) ^ (n & 7)) * 16;
    }

    for (int k0 = 0; k0 < K; k0 += 128) {
        __syncthreads();
        #pragma unroll
        for (int it = 0; it < 4; it++) {
            gld16(ap[it] + k0, sA + sdst[it]);
            gld16(bp[it] + k0, sB + sdst[it]);
        }
        __syncthreads();
        i32x8 bfr[4];
        #pragma unroll
        for (int j = 0; j < 4; j++) {
            i32x4* h = (i32x4*)&bfr[j];
            h[0] = *(const i32x4*)(sB + foB[j][0]);
            h[1] = *(const i32x4*)(sB + foB[j][1]);
        }
        #pragma unroll
        for (int i = 0; i < 4; i++) {
            i32x8 af;
            i32x4* h = (i32x4*)&af;
            h[0] = *(const i32x4*)(sA + foA[i][0]);
            h[1] = *(const i32x4*)(sA + foA[i][1]);
            #pragma unroll
            for (int j = 0; j < 4; j++)
                acc[i][j] = __builtin_amdgcn_mfma_scale_f32_16x16x128_f8f6f4(
                    af, bfr[j], acc[i][j], 0, 0,      // cbsz=fp8, blgp=fp8
                    0, SCALE1, 0, SCALE1);            // scales = 1.0
        }
    }
}

// ---------------- init: zero norm + loss accumulators ----------------
__global__ void init_kernel(float* __restrict__ qn2, float* __restrict__ kn2,
                            float* __restrict__ accf) {
    int t = blockIdx.x * 256 + threadIdx.x;
    if (t < BB * NN) { qn2[t] = 0.f; kn2[t] = 0.f; }
    if (t == 0) { ((double*)accf)[0] = 0.0; ((unsigned int*)accf)[2] = 0u; }
}

// ---------------- W fp32 -> fp8 (layout unchanged, c fast) ----------------
__global__ void conv_w(const float* __restrict__ Wq, const float* __restrict__ Wk,
                       uint8_t* __restrict__ Wq8, uint8_t* __restrict__ Wk8) {
    const int per = CC * CC / 4;
    int idx = blockIdx.x * 256 + threadIdx.x;
    if (idx >= 2 * per) return;
    const float4* src; uint8_t* dst; int i;
    if (idx < per) { src = (const float4*)Wq; dst = Wq8; i = idx; }
    else           { src = (const float4*)Wk; dst = Wk8; i = idx - per; }
    float4 v = src[i];
    *(uint32_t*)(dst + (size_t)i * 4) = pk2fp8(v.x, v.y) | (pk2fp8(v.z, v.w) << 16);
}

// ---------------- x fp32 [b][c][n] -> x8 fp8 same + xT8 fp8 [b][n][c] -----
__global__ void conv_x(const float* __restrict__ x, uint8_t* __restrict__ x8,
                       uint8_t* __restrict__ xT8) {
    __shared__ float tile[32][33];
    const int b = blockIdx.z;
    const int c0 = blockIdx.y * 32, n0 = blockIdx.x * 32;
    const int t = threadIdx.x;
    {
        const int c = t >> 3, n4 = (t & 7) * 4;
        const float4 v = *(const float4*)(x + ((size_t)b * CC + c0 + c) * NN + n0 + n4);
        *(uint32_t*)(x8 + ((size_t)b * CC + c0 + c) * NN + n0 + n4) =
            pk2fp8(v.x, v.y) | (pk2fp8(v.z, v.w) << 16);
        tile[c][n4] = v.x; tile[c][n4 + 1] = v.y;
        tile[c][n4 + 2] = v.z; tile[c][n4 + 3] = v.w;
    }
    __syncthreads();
    {
        const int n = t >> 3, c4 = (t & 7) * 4;
        uint32_t u = pk2fp8(tile[c4][n], tile[c4 + 1][n])
                   | (pk2fp8(tile[c4 + 2][n], tile[c4 + 3][n]) << 16);
        *(uint32_t*)(xT8 + ((size_t)b * NN + n0 + n) * CC + c0 + c4) = u;
    }
}

// ---------------- merged proj (q and k): outT[b][n][o] = sum_c xT[n][c]*W[o][c]+bias
// grid.z = b*2 + which; fused row-norm accumulation from fp32 accs. ----
__global__ __launch_bounds__(256) void gemm_proj(
    const uint8_t* __restrict__ xT8,
    const uint8_t* __restrict__ Wq8, const uint8_t* __restrict__ Wk8,
    const float* __restrict__ bq, const float* __restrict__ bk,
    uint8_t* __restrict__ qT8, uint8_t* __restrict__ kT8,
    float* __restrict__ qn2, float* __restrict__ kn2)
{
    __shared__ __align__(16) uint8_t sA[128 * 128];
    __shared__ __align__(16) uint8_t sB[128 * 128];
    const int z = blockIdx.z;
    const int b = z >> 1, which = z & 1;
    const uint8_t* Wb   = which ? Wk8 : Wq8;
    const float*   bias = which ? bk  : bq;
    uint8_t*       outT = which ? kT8 : qT8;
    float*         nrm  = which ? kn2 : qn2;
    const int m0 = blockIdx.y * 128;   // n
    const int n0 = blockIdx.x * 128;   // o
    f32x4 acc[4][4];
    const f32x4 zz = {0.f, 0.f, 0.f, 0.f};
    #pragma unroll
    for (int i = 0; i < 4; i++)
        #pragma unroll
        for (int j = 0; j < 4; j++) acc[i][j] = zz;
    mfma_mainloop_mx(xT8 + (size_t)b * NN * CC, Wb, CC, m0, n0, sA, sB, acc);
    const int t = threadIdx.x, lane = t & 63, w = t >> 6;
    const int wm = (w >> 1) * 64, wn = (w & 1) * 64;
    const int col = lane & 15, quad = lane >> 4;
    uint8_t* O = outT + (size_t)b * NN * CC;
    float sq[4][4];
    #pragma unroll
    for (int i = 0; i < 4; i++)
        #pragma unroll
        for (int r = 0; r < 4; r++) sq[i][r] = 0.f;
    #pragma unroll
    for (int j = 0; j < 4; j++) {
        const int gn = n0 + wn + j * 16 + col;     // o
        const float bv = bias[gn];
        #pragma unroll
        for (int i = 0; i < 4; i++) {
            const int gm = m0 + wm + i * 16 + quad * 4;   // n
            #pragma unroll
            for (int r = 0; r < 4; r++) {
                float v = acc[i][j][r] + bv;
                O[(size_t)(gm + r) * CC + gn] = f2fp8(v);
                sq[i][r] += v * v;
            }
        }
    }
    #pragma unroll
    for (int i = 0; i < 4; i++)
        #pragma unroll
        for (int r = 0; r < 4; r++) {
            float s = sq[i][r];
            #pragma unroll
            for (int o = 1; o < 16; o <<= 1) s += __shfl_xor(s, o, 64);
            if (col == 0) {
                const int gm = m0 + wm + i * 16 + quad * 4 + r;
                atomicAdd(&nrm[b * NN + gm], s);
            }
        }
}

// ---------------- energy: S[b][n][m] = sum_o qT[n][o]*kT[m][o] (bf16 out) --
__global__ __launch_bounds__(256) void gemm_energy(
    const uint8_t* __restrict__ qT8, const uint8_t* __restrict__ kT8,
    ushort_t* __restrict__ S)
{
    __shared__ __align__(16) uint8_t sA[128 * 128];
    __shared__ __align__(16) uint8_t sB[128 * 128];
    const int b = blockIdx.z;
    const int m0 = blockIdx.y * 128;   // n
    const int n0 = blockIdx.x * 128;   // m
    f32x4 acc[4][4];
    const f32x4 zz = {0.f, 0.f, 0.f, 0.f};
    #pragma unroll
    for (int i = 0; i < 4; i++)
        #pragma unroll
        for (int j = 0; j < 4; j++) acc[i][j] = zz;
    mfma_mainloop_mx(qT8 + (size_t)b * NN * CC, kT8 + (size_t)b * NN * CC, CC,
                     m0, n0, sA, sB, acc);
    const int t = threadIdx.x, lane = t & 63, w = t >> 6;
    const int wm = (w >> 1) * 64, wn = (w & 1) * 64;
    const int col = lane & 15, quad = lane >> 4;
    ushort_t* O = S + (size_t)b * NN * NN;
    #pragma unroll
    for (int i = 0; i < 4; i++) {
        const int gm = m0 + wm + i * 16 + quad * 4;
        #pragma unroll
        for (int j = 0; j < 4; j++) {
            const int gn = n0 + wn + j * 16 + col;
            #pragma unroll
            for (int r = 0; r < 4; r++)
                O[(size_t)(gm + r) * NN + gn] = f2bf(acc[i][j][r]);
        }
    }
}

// ---------------- softmax row n over m, scale rsqrt(qn2*kn2), inline mask,
// write att = mask*softmax*256 as fp8 (x256 escapes e4m3 subnormal floor) --
__global__ __launch_bounds__(256) void softmax_kernel(
    const ushort_t* __restrict__ S, uint8_t* __restrict__ att,
    const float* __restrict__ qn2, const float* __restrict__ kn2,
    const float* __restrict__ cam)
{
    const int n = blockIdx.x, b = blockIdx.y;
    const ushort_t* row = S + ((size_t)b * NN + n) * NN;
    uint8_t* orow = att + ((size_t)b * NN + n) * NN;
    const float qinv = rsqrtf(qn2[b * NN + n]);
    // inline bilinear mask for this query row
    const int y = n / WW, xx = n % WW;
    const float ys = (float)(y  * (CAMS - 1)) / (float)(HH - 1);
    const float xs = (float)(xx * (CAMS - 1)) / (float)(WW - 1);
    const int y0 = (int)ys, x0 = (int)xs;
    const int y1 = min(y0 + 1, CAMS - 1), x1 = min(x0 + 1, CAMS - 1);
    const float wy = ys - (float)y0, wx = xs - (float)x0;
    const float* cb = cam + (size_t)b * CAMS * CAMS;
    float c00 = cb[y0 * CAMS + x0]; if (c00 == 255.f) c00 = 0.f;
    float c01 = cb[y0 * CAMS + x1]; if (c01 == 255.f) c01 = 0.f;
    float c10 = cb[y1 * CAMS + x0]; if (c10 == 255.f) c10 = 0.f;
    float c11 = cb[y1 * CAMS + x1]; if (c11 == 255.f) c11 = 0.f;
    const float mv = (1.f - wy) * ((1.f - wx) * c00 + wx * c01)
                   +        wy  * ((1.f - wx) * c10 + wx * c11);
    const float mval = (mv > 0.f) ? 1.f : 0.f;

    const int t = threadIdx.x;
    float v[9];
    float vmax = -3.4e38f;
    #pragma unroll
    for (int i = 0; i < 9; i++) {
        int idx = t + i * 256;
        float s = bf2f(row[idx]) * qinv * rsqrtf(kn2[b * NN + idx]);
        v[i] = s;
        vmax = fmaxf(vmax, s);
    }
    __shared__ float red[8];
    int lane = t & 63, wid = t >> 6;
    #pragma unroll
    for (int o = 32; o; o >>= 1) vmax = fmaxf(vmax, __shfl_down(vmax, o, 64));
    if (!lane) red[wid] = vmax;
    __syncthreads();
    vmax = fmaxf(fmaxf(red[0], red[1]), fmaxf(red[2], red[3]));
    float s = 0.f;
    #pragma unroll
    for (int i = 0; i < 9; i++) { v[i] = __expf(v[i] - vmax); s += v[i]; }
    #pragma unroll
    for (int o = 32; o; o >>= 1) s += __shfl_down(s, o, 64);
    if (!lane) red[4 + wid] = s;
    __syncthreads();
    s = red[4] + red[5] + red[6] + red[7];
    const float scale = mval * 256.f / s;
    #pragma unroll
    for (int i = 0; i < 9; i++) orow[t + i * 256] = f2fp8(v[i] * scale);
}

// ---------------- out: new_x[c][n] = sum_m x8[c][m]*att[n][m]; fused loss --
__global__ __launch_bounds__(256) void gemm_out_loss(
    const uint8_t* __restrict__ x8, const uint8_t* __restrict__ att,
    const float* __restrict__ x, const float* __restrict__ gamma,
    float* __restrict__ accf)
{
    __shared__ __align__(16) uint8_t sA[128 * 128];
    __shared__ __align__(16) uint8_t sB[128 * 128];
    const int b = blockIdx.z;
    const int m0 = blockIdx.y * 128;   // c
    const int n0 = blockIdx.x * 128;   // n
    f32x4 acc[4][4];
    const f32x4 zz = {0.f, 0.f, 0.f, 0.f};
    #pragma unroll
    for (int i = 0; i < 4; i++)
        #pragma unroll
        for (int j = 0; j < 4; j++) acc[i][j] = zz;
    mfma_mainloop_mx(x8 + (size_t)b * CC * NN, att + (size_t)b * NN * NN, NN,
                     m0, n0, sA, sB, acc);
    const int t = threadIdx.x, lane = t & 63, w = t >> 6;
    const int wm = (w >> 1) * 64, wn = (w & 1) * 64;
    const int col = lane & 15, quad = lane >> 4;
    const float g = gamma[0] * (1.f / 256.f);   // undo att x256 pre-scale
    const float* Xb = x + (size_t)b * CC * NN;
    float lsum = 0.f;
    unsigned int lcnt = 0;
    #pragma unroll
    for (int i = 0; i < 4; i++) {
        const int gm = m0 + wm + i * 16 + quad * 4;   // c
        #pragma unroll
        for (int j = 0; j < 4; j++) {
            const int gn = n0 + wn + j * 16 + col;    // n
            #pragma unroll
            for (int r = 0; r < 4; r++) {
                float xv = Xb[(size_t)(gm + r) * NN + gn];
                float d = xv - g * acc[i][j][r];
                float r2 = d * d;
                lsum += r2;
                lcnt += (r2 != 0.f) ? 1u : 0u;
            }
        }
    }
    #pragma unroll
    for (int o = 32; o; o >>= 1) {
        lsum += __shfl_down(lsum, o, 64);
        lcnt += __shfl_down(lcnt, o, 64);
    }
    __shared__ float rs[4];
    __shared__ unsigned int rc[4];
    if (!lane) { rs[w] = lsum; rc[w] = lcnt; }
    __syncthreads();
    if (t == 0) {
        double tot = (double)rs[0] + rs[1] + rs[2] + rs[3];
        unsigned int ct = rc[0] + rc[1] + rc[2] + rc[3];
        atomicAdd((double*)accf, tot);
        atomicAdd(((unsigned int*)accf) + 2, ct);
    }
}

__global__ void finalize_kernel(const float* __restrict__ accf, float* __restrict__ out) {
    double s = ((const double*)accf)[0];
    unsigned int c = ((const unsigned int*)accf)[2];
    out[0] = (float)(s / (double)c);
}

extern "C" void kernel_launch(void* const* d_in, const int* in_sizes, int n_in,
                              void* d_out, int out_size, void* d_ws, size_t ws_size,
                              hipStream_t stream) {
    const float* x     = (const float*)d_in[0];
    const float* cam   = (const float*)d_in[1];
    const float* Wq    = (const float*)d_in[2];
    const float* bq    = (const float*)d_in[3];
    const float* Wk    = (const float*)d_in[4];
    const float* bk    = (const float*)d_in[5];
    const float* gamma = (const float*)d_in[6];

    uint8_t* ws = (uint8_t*)d_ws;
    size_t off = 0;
    auto alloc = [&](size_t bytes) {
        void* p = ws + off;
        off = (off + bytes + 255) & ~(size_t)255;
        return p;
    };
    uint8_t*  qT8  = (uint8_t*)alloc((size_t)BB * NN * CC);
    uint8_t*  kT8  = (uint8_t*)alloc((size_t)BB * NN * CC);
    uint8_t*  xT8  = (uint8_t*)alloc((size_t)BB * NN * CC);
    uint8_t*  x8   = (uint8_t*)alloc((size_t)BB * CC * NN);
    uint8_t*  att  = (uint8_t*)alloc((size_t)BB * NN * NN);
    ushort_t* S    = (ushort_t*)alloc((size_t)BB * NN * NN * 2);
    uint8_t*  Wq8  = (uint8_t*)alloc((size_t)CC * CC);
    uint8_t*  Wk8  = (uint8_t*)alloc((size_t)CC * CC);
    float*    qn2  = (float*)alloc((size_t)BB * NN * 4);
    float*    kn2  = (float*)alloc((size_t)BB * NN * 4);
    float*    acc  = (float*)alloc(16);

    hipLaunchKernelGGL(init_kernel, dim3((BB * NN + 255) / 256), dim3(256), 0, stream,
                       qn2, kn2, acc);
    hipLaunchKernelGGL(conv_w, dim3(2 * CC * CC / 4 / 256), dim3(256), 0, stream,
                       Wq, Wk, Wq8, Wk8);
    hipLaunchKernelGGL(conv_x, dim3(NN / 32, CC / 32, BB), dim3(256), 0, stream,
                       x, x8, xT8);
    hipLaunchKernelGGL(gemm_proj, dim3(CC / 128, NN / 128, BB * 2), dim3(256), 0, stream,
                       xT8, Wq8, Wk8, bq, bk, qT8, kT8, qn2, kn2);
    hipLaunchKernelGGL(gemm_energy, dim3(NN / 128, NN / 128, BB), dim3(256), 0, stream,
                       qT8, kT8, S);
    hipLaunchKernelGGL(softmax_kernel, dim3(NN, BB), dim3(256), 0, stream,
                       S, att, qn2, kn2, cam);
    hipLaunchKernelGGL(gemm_out_loss, dim3(NN / 128, CC / 128, BB), dim3(256), 0, stream,
                       x8, att, x, gamma, acc);
    hipLaunchKernelGGL(finalize_kernel, dim3(1), dim3(1), 0, stream, acc, (float*)d_out);
}